// Round 2
// baseline (1068.388 us; speedup 1.0000x reference)
//
#include <hip/hip_runtime.h>
#include <stdint.h>

// ---------- helpers ----------
typedef __attribute__((ext_vector_type(8))) short bf16x8;
typedef __attribute__((ext_vector_type(4))) float f32x4;

__device__ __forceinline__ float b2f(unsigned short s) {
    unsigned int u = ((unsigned int)s) << 16;
    return __builtin_bit_cast(float, u);
}
__device__ __forceinline__ unsigned short f2b(float f) {
    unsigned int u = __builtin_bit_cast(unsigned int, f);
    u += 0x7FFFu + ((u >> 16) & 1u);   // RNE
    return (unsigned short)(u >> 16);
}

#define EPS_ATTN 1e-8f
#define LN_EPS 1e-5f
#define SCALE 0.0625f  // 256^-0.5

// ---------- prep: W3 in MFMA B-fragment order ----------
__global__ __launch_bounds__(256) void k_prep(const float* __restrict__ wk,
                                              const float* __restrict__ wv,
                                              unsigned short* __restrict__ W3) {
    int g = blockIdx.x * 256 + threadIdx.x;   // 131072
    int j = g & 7;
    int f = (g >> 3) & 1023;
    int stage = g >> 13;
    int p = f & 15, qq = (f >> 4) & 3, ntl = f >> 6;
    int kc = stage >> 1, half_ = stage & 1;
    int k = kc * 32 + qq * 8 + j;
    int n = half_ * 256 + ntl * 16 + p;
    float v = (n < 256) ? wk[k * 256 + n] : wv[k * 256 + (n - 256)];
    W3[g] = f2b(v);
}

// ---------- slot init ----------
__global__ __launch_bounds__(256) void k_init(const float* __restrict__ sm,
                                              const float* __restrict__ slv,
                                              const float* __restrict__ noise,
                                              float* __restrict__ slots) {
    int idx = blockIdx.x * 256 + threadIdx.x; // 131072
    int d = idx & 255;
    slots[idx] = sm[d] + expf(slv[d]) * noise[idx];
}

// ---------- fused LN(inputs) + K/V projection ----------
// B fragments loaded DIRECTLY global->VGPR (W3 is L2-resident, lane*16B coalesced),
// so the MFMA main loop has ZERO barriers. Wave w owns a 64row x 128col output strip.
// K written [bh][n][32] via LDS restage (64B rows). V written TRANSPOSED [bh][d][4096]
// via a second LDS restage (even-XOR chunk swizzle, 128B row segments out).
__global__ __launch_bounds__(256, 2) void k_kv(
    const float* __restrict__ x, const float* __restrict__ lnw, const float* __restrict__ lnb,
    const unsigned short* __restrict__ W3, const float* __restrict__ bk, const float* __restrict__ bv,
    unsigned short* __restrict__ Kb, unsigned short* __restrict__ Vb) {
    __shared__ __align__(16) unsigned short sh[33792];  // 67,584 B
    unsigned short* As   = sh;            // 16384 u: A frags (xor-swizzled); aliased as repK in epilogue
    unsigned short* repV = sh + 16384;    // 16384 u: V^T restage
    float* bL = (float*)(sh + 32768);     // 512 floats (biases)
    int t = threadIdx.x;
    int w = t >> 6, lane = t & 63;
    int p = lane & 15, q = lane >> 4;

    if (t < 128) {
        float4 bb = (t < 64) ? ((const float4*)bk)[t] : ((const float4*)bv)[t - 64];
        *(float4*)&bL[t * 4] = bb;
    }

    // ---- LN(x) -> As (bf16, xor-swizzled A fragments) ----
    float4 lw  = ((const float4*)lnw)[lane];
    float4 lbv = ((const float4*)lnb)[lane];
    float4 xv[16];
    const float* xbase = x + ((size_t)blockIdx.x * 64 + w * 16) * 256;
    #pragma unroll
    for (int i = 0; i < 16; ++i) xv[i] = ((const float4*)(xbase + i * 256))[lane];
    int kcw = lane >> 3, qw = (lane >> 1) & 3, j0 = (lane & 1) * 4;
    #pragma unroll
    for (int i = 0; i < 16; ++i) {
        float4 v = xv[i];
        float s0 = v.x + v.y + v.z + v.w;
        float s1 = v.x * v.x + v.y * v.y + v.z * v.z + v.w * v.w;
        #pragma unroll
        for (int o = 1; o < 64; o <<= 1) { s0 += __shfl_xor(s0, o); s1 += __shfl_xor(s1, o); }
        float mean = s0 * (1.0f / 256.0f);
        float var  = s1 * (1.0f / 256.0f) - mean * mean;
        float rstd = rsqrtf(var + LN_EPS);
        ushort4 pk;
        pk.x = f2b((v.x - mean) * rstd * lw.x + lbv.x);
        pk.y = f2b((v.y - mean) * rstd * lw.y + lbv.y);
        pk.z = f2b((v.z - mean) * rstd * lw.z + lbv.z);
        pk.w = f2b((v.w - mean) * rstd * lw.w + lbv.w);
        int pos = (qw * 16 + i) ^ kcw;
        *(ushort4*)&As[((w * 8 + kcw) * 64 + pos) * 8 + j0] = pk;
    }
    __syncthreads();

    // ---- barrier-free MFMA main loop ----
    // wave strip: cols [w*128, w*128+128) => half = w>>1, ntl in [ (w&1)*8, +8 )
    f32x4 acc[4][8];
    f32x4 zero = {0.f, 0.f, 0.f, 0.f};
    #pragma unroll
    for (int rt = 0; rt < 4; ++rt)
        #pragma unroll
        for (int ct = 0; ct < 8; ++ct) acc[rt][ct] = zero;

    const unsigned short* Wb = W3 + (size_t)(w >> 1) * 8192 + (size_t)((w & 1) * 8) * 512 + lane * 8;
    #pragma unroll 2
    for (int kc = 0; kc < 8; ++kc) {
        bf16x8 af[4];
        #pragma unroll
        for (int rt = 0; rt < 4; ++rt)
            af[rt] = *(const bf16x8*)&As[((rt * 8 + kc) * 64 + ((q * 16 + p) ^ kc)) * 8];
        #pragma unroll
        for (int ct = 0; ct < 8; ++ct) {
            bf16x8 bf = *(const bf16x8*)(Wb + (size_t)kc * 16384 + ct * 512);
            #pragma unroll
            for (int rt = 0; rt < 4; ++rt)
                acc[rt][ct] = __builtin_amdgcn_mfma_f32_16x16x32_bf16(af[rt], bf, acc[rt][ct], 0, 0, 0);
        }
    }
    __syncthreads();   // As reads done; safe to overwrite as repK

    unsigned short* repK = As;
    int b_  = blockIdx.x >> 6;
    int n0g = (blockIdx.x & 63) * 64;

    if (w < 2) {
        // K strip (global cols 0..255): stage [h][n][32] tile
        #pragma unroll
        for (int ct = 0; ct < 8; ++ct) {
            int col = w * 128 + ct * 16 + p;
            float bias = bL[col];
            int hl = col >> 5, dh = col & 31;
            #pragma unroll
            for (int rt = 0; rt < 4; ++rt) {
                #pragma unroll
                for (int r = 0; r < 4; ++r) {
                    int nl = rt * 16 + q * 4 + r;
                    repK[(hl * 64 + nl) * 32 + dh] = f2b(acc[rt][ct][r] + bias);
                }
            }
        }
    } else {
        // V strip (global cols 256..511 -> vrow 0..255): stage [vrow][n] with even-XOR chunk swizzle
        #pragma unroll
        for (int ct = 0; ct < 8; ++ct) {
            int vrow = (w - 2) * 128 + ct * 16 + p;
            float bias = bL[256 + vrow];
            #pragma unroll
            for (int rt = 0; rt < 4; ++rt) {
                int chunk = (rt * 4 + q) ^ (p & 14);
                ushort4 pk;
                pk.x = f2b(acc[rt][ct][0] + bias);
                pk.y = f2b(acc[rt][ct][1] + bias);
                pk.z = f2b(acc[rt][ct][2] + bias);
                pk.w = f2b(acc[rt][ct][3] + bias);
                *(ushort4*)&repV[vrow * 64 + chunk * 4] = pk;
            }
        }
    }
    __syncthreads();

    // K out: fully coalesced 4KB per h-slice
    #pragma unroll
    for (int i = 0; i < 8; ++i) {
        uint4 vd = *(const uint4*)&repK[(i * 256 + t) * 8];
        *(uint4*)(Kb + (((size_t)b_ * 8 + i) * 4096 + n0g) * 32 + t * 8) = vd;
    }
    // V out: 8 rows x 128B segments per wave-instruction
    #pragma unroll
    for (int i = 0; i < 8; ++i) {
        int vrow = i * 32 + (t >> 3);
        int c16 = t & 7;
        uint4 vd = *(const uint4*)&repV[vrow * 64 + ((2 * c16) ^ (vrow & 14)) * 4];
        *(uint4*)(Vb + ((size_t)(b_ * 8 + (vrow >> 5)) * 32 + (vrow & 31)) * 4096 + n0g + c16 * 8) = vd;
    }
}

// ---------- q projection ----------
__global__ __launch_bounds__(256) void k_q(
    const float* __restrict__ slots, const float* __restrict__ lnw, const float* __restrict__ lnb,
    const float* __restrict__ wq, const float* __restrict__ bq, float* __restrict__ qg) {
    __shared__ float sln[256];
    __shared__ float red[8];
    int t = threadIdx.x;
    int row = blockIdx.x;
    float v = slots[(size_t)row * 256 + t];
    float s0 = v, s1 = v * v;
    #pragma unroll
    for (int off = 1; off < 64; off <<= 1) { s0 += __shfl_xor(s0, off); s1 += __shfl_xor(s1, off); }
    if ((t & 63) == 0) { red[t >> 6] = s0; red[4 + (t >> 6)] = s1; }
    __syncthreads();
    float ts0 = red[0] + red[1] + red[2] + red[3];
    float ts1 = red[4] + red[5] + red[6] + red[7];
    float mean = ts0 * (1.f / 256.f);
    float var  = ts1 * (1.f / 256.f) - mean * mean;
    float rstd = rsqrtf(var + LN_EPS);
    sln[t] = (v - mean) * rstd * lnw[t] + lnb[t];
    __syncthreads();
    float acc = bq[t];
    #pragma unroll 4
    for (int k = 0; k < 256; ++k) acc += sln[k] * wq[k * 256 + t];
    int b = row >> 3, sl = row & 7;
    qg[(size_t)b * 2048 + (t >> 5) * 256 + sl * 32 + (t & 31)] = acc;
}

// ---------- attention sweep: MFMA QK^T (swapped) + MFMA PV, no main-loop LDS ----------
__global__ __launch_bounds__(512) void k_attn(
    const unsigned short* __restrict__ Kg, const unsigned short* __restrict__ VTg,
    const float* __restrict__ qg, float* __restrict__ upd_raw, float* __restrict__ rowsum,
    float* __restrict__ attn_out, int last) {
    __shared__ float supd[8][256];
    __shared__ float srs[8][8];
    int t = threadIdx.x;
    int w = t >> 6, lane = t & 63;
    int c = lane & 15;     // QK-C col = slot s ; PV A row = d ; PV-C col = s
    int g = lane >> 4;     // lane group

    int bh = blockIdx.x;
    const unsigned short* Kbh = Kg  + (size_t)bh * 4096 * 32;
    const unsigned short* Vbh = VTg + (size_t)bh * 32 * 4096;

    // Q B-fragment: lane holds Q[s=c][d=g*8+j], bf16 hi+lo split; zero for s>=8.
    bf16x8 qhi = {0,0,0,0,0,0,0,0};
    bf16x8 qlo = {0,0,0,0,0,0,0,0};
    if (c < 8) {
        const float* qp = qg + (size_t)bh * 256 + c * 32 + g * 8;
        #pragma unroll
        for (int j = 0; j < 8; ++j) {
            float qv = qp[j];
            unsigned short hb = f2b(qv);
            qhi[j] = (short)hb;
            qlo[j] = (short)f2b(qv - b2f(hb));
        }
    }

    f32x4 zero = {0.f, 0.f, 0.f, 0.f};
    f32x4 accL = zero, accH = zero;
    float rs = 0.f;
    int nb0 = w * 512;

    #pragma unroll 2
    for (int pr = 0; pr < 16; ++pr) {
        int base = nb0 + pr * 32;
        bf16x8 k0 = *(const bf16x8*)(Kbh + (size_t)(base + c) * 32 + g * 8);
        bf16x8 k1 = *(const bf16x8*)(Kbh + (size_t)(base + 16 + c) * 32 + g * 8);
        const unsigned short* vlo = Vbh + (size_t)c * 4096 + base + g * 4;
        const unsigned short* vhi = Vbh + (size_t)(c + 16) * 4096 + base + g * 4;
        union { ushort4 h[2]; bf16x8 v; } V0, V1;
        V0.h[0] = *(const ushort4*)vlo;
        V0.h[1] = *(const ushort4*)(vlo + 16);
        V1.h[0] = *(const ushort4*)vhi;
        V1.h[1] = *(const ushort4*)(vhi + 16);

        f32x4 s0 = __builtin_amdgcn_mfma_f32_16x16x32_bf16(k0, qhi, zero, 0, 0, 0);
        s0 = __builtin_amdgcn_mfma_f32_16x16x32_bf16(k0, qlo, s0, 0, 0, 0);
        f32x4 s1 = __builtin_amdgcn_mfma_f32_16x16x32_bf16(k1, qhi, zero, 0, 0, 0);
        s1 = __builtin_amdgcn_mfma_f32_16x16x32_bf16(k1, qlo, s1, 0, 0, 0);

        float d0[4], d1[4];
        #pragma unroll
        for (int r = 0; r < 4; ++r) { d0[r] = s0[r] * SCALE; d1[r] = s1[r] * SCALE; }
        float m = fmaxf(fmaxf(fmaxf(d0[0], d0[1]), fmaxf(d0[2], d0[3])),
                        fmaxf(fmaxf(d1[0], d1[1]), fmaxf(d1[2], d1[3])));
        m = fmaxf(m, __shfl_xor(m, 1));
        m = fmaxf(m, __shfl_xor(m, 2));
        m = fmaxf(m, __shfl_xor(m, 4));
        m = fmaxf(m, __shfl_xor(m, 8));
        float a0[4], a1[4];
        #pragma unroll
        for (int r = 0; r < 4; ++r) {
            float e0 = __expf(d0[r] - m);
            float e1 = __expf(d1[r] - m);
            float t0 = e0;
            t0 += __shfl_xor(t0, 1); t0 += __shfl_xor(t0, 2); t0 += __shfl_xor(t0, 4);
            float t1 = e1;
            t1 += __shfl_xor(t1, 1); t1 += __shfl_xor(t1, 2); t1 += __shfl_xor(t1, 4);
            a0[r] = e0 * (1.0f / t0) + EPS_ATTN;
            a1[r] = e1 * (1.0f / t1) + EPS_ATTN;
            rs += a0[r] + a1[r];
        }
        if (last && c < 8) {
            float4 st0 = {a0[0], a0[1], a0[2], a0[3]};
            float4 st1 = {a1[0], a1[1], a1[2], a1[3]};
            float* ap = attn_out + ((size_t)bh * 8 + c) * 4096 + base + g * 4;
            *(float4*)ap = st0;
            *(float4*)(ap + 16) = st1;
        }
        bf16x8 pah, pal;
        float af[8] = {a0[0], a0[1], a0[2], a0[3], a1[0], a1[1], a1[2], a1[3]};
        #pragma unroll
        for (int j = 0; j < 8; ++j) {
            unsigned short hb = f2b(af[j]);
            pah[j] = (short)hb;
            pal[j] = (short)f2b(af[j] - b2f(hb));
        }
        accL = __builtin_amdgcn_mfma_f32_16x16x32_bf16(V0.v, pah, accL, 0, 0, 0);
        accL = __builtin_amdgcn_mfma_f32_16x16x32_bf16(V0.v, pal, accL, 0, 0, 0);
        accH = __builtin_amdgcn_mfma_f32_16x16x32_bf16(V1.v, pah, accH, 0, 0, 0);
        accH = __builtin_amdgcn_mfma_f32_16x16x32_bf16(V1.v, pal, accH, 0, 0, 0);
    }

    rs += __shfl_xor(rs, 16);
    rs += __shfl_xor(rs, 32);
    if (lane < 8) srs[w][lane] = rs;
    if (c < 8) {
        float* up = &supd[w][c * 32 + g * 4];
        up[0]  = accL[0]; up[1]  = accL[1]; up[2]  = accL[2]; up[3]  = accL[3];
        up[16] = accH[0]; up[17] = accH[1]; up[18] = accH[2]; up[19] = accH[3];
    }
    __syncthreads();
    if (t < 256) {
        float v = 0.f;
        #pragma unroll
        for (int ww = 0; ww < 8; ++ww) v += supd[ww][t];
        upd_raw[(size_t)bh * 256 + t] = v;
    }
    if (t < 8) {
        float v = 0.f;
        #pragma unroll
        for (int ww = 0; ww < 8; ++ww) v += srs[ww][t];
        rowsum[bh * 8 + t] = v;
    }
}

// ========== slot-update stage kernels (col-split, LDS row-broadcast) ==========
__global__ __launch_bounds__(256) void k_gA(
    const float* __restrict__ upd_raw, const float* __restrict__ rowsum,
    const float* __restrict__ wo, const float* __restrict__ bo, float* __restrict__ O) {
    __shared__ float Ul[8][256];
    __shared__ float Pp[4][8][64];
    int t = threadIdx.x;
    int b = blockIdx.x >> 2, cc = blockIdx.x & 3;
    int colbase = cc * 64;
    {
        int r = t >> 5, d0 = (t & 31) * 8;
        int h = d0 >> 5;
        float inv = 1.0f / fmaxf(rowsum[(b * 8 + h) * 8 + r], 1e-12f);
        const float* up = upd_raw + (size_t)(b * 8 + h) * 256 + r * 32 + (d0 & 31);
        float4 u0 = *(const float4*)up;
        float4 u1 = *(const float4*)(up + 4);
        Ul[r][d0 + 0] = u0.x * inv; Ul[r][d0 + 1] = u0.y * inv;
        Ul[r][d0 + 2] = u0.z * inv; Ul[r][d0 + 3] = u0.w * inv;
        Ul[r][d0 + 4] = u1.x * inv; Ul[r][d0 + 5] = u1.y * inv;
        Ul[r][d0 + 6] = u1.z * inv; Ul[r][d0 + 7] = u1.w * inv;
    }
    __syncthreads();
    int c = t & 63, kq = t >> 6;
    float acc[8] = {0.f,0.f,0.f,0.f,0.f,0.f,0.f,0.f};
    const float* wp = wo + (size_t)(kq * 64) * 256 + colbase + c;
    #pragma unroll 16
    for (int k = 0; k < 64; ++k) {
        float wv_ = wp[(size_t)k * 256];
        int kk = kq * 64 + k;
        #pragma unroll
        for (int r = 0; r < 8; ++r) acc[r] += Ul[r][kk] * wv_;
    }
    #pragma unroll
    for (int r = 0; r < 8; ++r) Pp[kq][r][c] = acc[r];
    __syncthreads();
    #pragma unroll
    for (int j = 0; j < 2; ++j) {
        int o = t * 2 + j;
        int r = o >> 6, c2 = o & 63;
        float v = Pp[0][r][c2] + Pp[1][r][c2] + Pp[2][r][c2] + Pp[3][r][c2] + bo[colbase + c2];
        O[(size_t)(b * 8 + r) * 256 + colbase + c2] = v;
    }
}

__global__ __launch_bounds__(256) void k_gB(
    const float* __restrict__ O, const float* __restrict__ slin,
    const float* __restrict__ wih, const float* __restrict__ bih,
    const float* __restrict__ whh, const float* __restrict__ bhh,
    float* __restrict__ gcomb, float* __restrict__ xn, float* __restrict__ hn) {
    __shared__ float Ol[8][256], Hl[8][256];
    __shared__ float Px[2][8][128], Ph[2][8][128];
    int t = threadIdx.x;
    int b = blockIdx.x / 6, cc = blockIdx.x % 6;
    int colbase = cc * 128;
    {
        int r = t >> 5, d0 = (t & 31) * 8;
        const float* op = O + (size_t)(b * 8 + r) * 256 + d0;
        const float* hp = slin + (size_t)(b * 8 + r) * 256 + d0;
        *(float4*)&Ol[r][d0]     = *(const float4*)op;
        *(float4*)&Ol[r][d0 + 4] = *(const float4*)(op + 4);
        *(float4*)&Hl[r][d0]     = *(const float4*)hp;
        *(float4*)&Hl[r][d0 + 4] = *(const float4*)(hp + 4);
    }
    __syncthreads();
    int c = t & 127, kh = t >> 7;
    float ax[8] = {0.f,0.f,0.f,0.f,0.f,0.f,0.f,0.f};
    float ah[8] = {0.f,0.f,0.f,0.f,0.f,0.f,0.f,0.f};
    const float* wxp = wih + (size_t)(kh * 128) * 768 + colbase + c;
    const float* whp = whh + (size_t)(kh * 128) * 768 + colbase + c;
    #pragma unroll 8
    for (int k = 0; k < 128; ++k) {
        float wx = wxp[(size_t)k * 768];
        float wh = whp[(size_t)k * 768];
        int kk = kh * 128 + k;
        #pragma unroll
        for (int r = 0; r < 8; ++r) { ax[r] += Ol[r][kk] * wx; ah[r] += Hl[r][kk] * wh; }
    }
    #pragma unroll
    for (int r = 0; r < 8; ++r) { Px[kh][r][c] = ax[r]; Ph[kh][r][c] = ah[r]; }
    __syncthreads();
    #pragma unroll
    for (int j = 0; j < 4; ++j) {
        int o = t * 4 + j;               // [0,1024)
        int r = o >> 7, c2 = o & 127;
        int cg = colbase + c2;
        int row = b * 8 + r;
        float vx = Px[0][r][c2] + Px[1][r][c2] + bih[cg];
        float vh = Ph[0][r][c2] + Ph[1][r][c2] + bhh[cg];
        if (cg < 512) {
            gcomb[(size_t)row * 512 + cg] = vx + vh;
        } else {
            xn[(size_t)row * 256 + cg - 512] = vx;
            hn[(size_t)row * 256 + cg - 512] = vh;
        }
    }
}

__global__ __launch_bounds__(256) void k_gC(
    const float* __restrict__ gcomb, const float* __restrict__ xn, const float* __restrict__ hn,
    const float* __restrict__ slin, const float* __restrict__ lnfw, const float* __restrict__ lnfb,
    float* __restrict__ slout, float* __restrict__ F) {
    __shared__ float red[8];
    int t = threadIdx.x, row = blockIdx.x;
    float a_r = gcomb[(size_t)row * 512 + t];
    float a_z = gcomb[(size_t)row * 512 + 256 + t];
    float xnv = xn[(size_t)row * 256 + t];
    float hnv = hn[(size_t)row * 256 + t];
    float hp  = slin[(size_t)row * 256 + t];
    float rg = 1.f / (1.f + expf(-a_r));
    float zg = 1.f / (1.f + expf(-a_z));
    float ng = tanhf(xnv + rg * hnv);
    float s1 = (1.f - zg) * ng + zg * hp;
    slout[(size_t)row * 256 + t] = s1;
    float s0 = s1, sq = s1 * s1;
    #pragma unroll
    for (int o = 1; o < 64; o <<= 1) { s0 += __shfl_xor(s0, o); sq += __shfl_xor(sq, o); }
    if ((t & 63) == 0) { red[t >> 6] = s0; red[4 + (t >> 6)] = sq; }
    __syncthreads();
    float ts0 = red[0] + red[1] + red[2] + red[3];
    float ts1 = red[4] + red[5] + red[6] + red[7];
    float mean = ts0 * (1.f / 256.f);
    float var  = ts1 * (1.f / 256.f) - mean * mean;
    float rstd = rsqrtf(var + LN_EPS);
    F[(size_t)row * 256 + t] = (s1 - mean) * rstd * lnfw[t] + lnfb[t];
}

__global__ __launch_bounds__(256) void k_gD(
    const float* __restrict__ F, const float* __restrict__ w1, const float* __restrict__ b1,
    float* __restrict__ H1) {
    __shared__ float Fl[8][256];
    __shared__ float Pp[4][8][64];
    int t = threadIdx.x;
    int b = blockIdx.x >> 2, cc = blockIdx.x & 3;
    int colbase = cc * 64;
    {
        int r = t >> 5, d0 = (t & 31) * 8;
        const float* fp = F + (size_t)(b * 8 + r) * 256 + d0;
        *(float4*)&Fl[r][d0]     = *(const float4*)fp;
        *(float4*)&Fl[r][d0 + 4] = *(const float4*)(fp + 4);
    }
    __syncthreads();
    int c = t & 63, kq = t >> 6;
    float acc[8] = {0.f,0.f,0.f,0.f,0.f,0.f,0.f,0.f};
    const float* wp = w1 + (size_t)(kq * 64) * 256 + colbase + c;
    #pragma unroll 16
    for (int k = 0; k < 64; ++k) {
        float wv_ = wp[(size_t)k * 256];
        int kk = kq * 64 + k;
        #pragma unroll
        for (int r = 0; r < 8; ++r) acc[r] += Fl[r][kk] * wv_;
    }
    #pragma unroll
    for (int r = 0; r < 8; ++r) Pp[kq][r][c] = acc[r];
    __syncthreads();
    #pragma unroll
    for (int j = 0; j < 2; ++j) {
        int o = t * 2 + j;
        int r = o >> 6, c2 = o & 63;
        float v = Pp[0][r][c2] + Pp[1][r][c2] + Pp[2][r][c2] + Pp[3][r][c2] + b1[colbase + c2];
        H1[(size_t)(b * 8 + r) * 256 + colbase + c2] = fmaxf(v, 0.f);
    }
}

__global__ __launch_bounds__(256) void k_gE(
    const float* __restrict__ H1, const float* __restrict__ w2, const float* __restrict__ b2,
    float* __restrict__ slout) {
    __shared__ float Hl[8][256];
    __shared__ float Pp[4][8][64];
    int t = threadIdx.x;
    int b = blockIdx.x >> 2, cc = blockIdx.x & 3;
    int colbase = cc * 64;
    {
        int r = t >> 5, d0 = (t & 31) * 8;
        const float* hp = H1 + (size_t)(b * 8 + r) * 256 + d0;
        *(float4*)&Hl[r][d0]     = *(const float4*)hp;
        *(float4*)&Hl[r][d0 + 4] = *(const float4*)(hp + 4);
    }
    __syncthreads();
    int c = t & 63, kq = t >> 6;
    float acc[8] = {0.f,0.f,0.f,0.f,0.f,0.f,0.f,0.f};
    const float* wp = w2 + (size_t)(kq * 64) * 256 + colbase + c;
    #pragma unroll 16
    for (int k = 0; k < 64; ++k) {
        float wv_ = wp[(size_t)k * 256];
        int kk = kq * 64 + k;
        #pragma unroll
        for (int r = 0; r < 8; ++r) acc[r] += Hl[r][kk] * wv_;
    }
    #pragma unroll
    for (int r = 0; r < 8; ++r) Pp[kq][r][c] = acc[r];
    __syncthreads();
    #pragma unroll
    for (int j = 0; j < 2; ++j) {
        int o = t * 2 + j;
        int r = o >> 6, c2 = o & 63;
        size_t idx = (size_t)(b * 8 + r) * 256 + colbase + c2;
        float v = Pp[0][r][c2] + Pp[1][r][c2] + Pp[2][r][c2] + Pp[3][r][c2] + b2[colbase + c2];
        slout[idx] = slout[idx] + v;
    }
}

// ---------- final attn normalization (float4) ----------
__global__ __launch_bounds__(256) void k_scale(float* __restrict__ attn, const float* __restrict__ rowsum) {
    size_t i4 = ((size_t)blockIdx.x * 256 + threadIdx.x) * 4;
    int row = (int)(i4 >> 12);
    float inv = 1.0f / fmaxf(rowsum[row], 1e-12f);
    float4 v = *(float4*)(attn + i4);
    v.x *= inv; v.y *= inv; v.z *= inv; v.w *= inv;
    *(float4*)(attn + i4) = v;
}

extern "C" void kernel_launch(void* const* d_in, const int* in_sizes, int n_in,
                              void* d_out, int out_size, void* d_ws, size_t ws_size,
                              hipStream_t stream) {
    const float* inputs = (const float*)d_in[0];
    const float* noise  = (const float*)d_in[1];
    const float* sm     = (const float*)d_in[2];
    const float* slv    = (const float*)d_in[3];
    const float* wq     = (const float*)d_in[4];
    const float* bq     = (const float*)d_in[5];
    const float* wk     = (const float*)d_in[6];
    const float* bk     = (const float*)d_in[7];
    const float* wv     = (const float*)d_in[8];
    const float* bv     = (const float*)d_in[9];
    const float* wo     = (const float*)d_in[10];
    const float* bo     = (const float*)d_in[11];
    const float* wih    = (const float*)d_in[12];
    const float* bih    = (const float*)d_in[13];
    const float* whh    = (const float*)d_in[14];
    const float* bhh    = (const float*)d_in[15];
    const float* w1     = (const float*)d_in[16];
    const float* b1     = (const float*)d_in[17];
    const float* w2     = (const float*)d_in[18];
    const float* b2     = (const float*)d_in[19];
    const float* lniw   = (const float*)d_in[20];
    const float* lnib   = (const float*)d_in[21];
    const float* lnsw   = (const float*)d_in[22];
    const float* lnsb   = (const float*)d_in[23];
    const float* lnfw   = (const float*)d_in[24];
    const float* lnfb   = (const float*)d_in[25];

    char* ws = (char*)d_ws;
    unsigned short* Kb = (unsigned short*)ws;                         // 134,217,728  [bh][n][32]
    unsigned short* Vb = (unsigned short*)(ws + 134217728ull);        // 134,217,728  [bh][d][4096] (transposed)
    float* slotsA  = (float*)(ws + 268435456ull);                     // 524,288
    float* slotsB  = (float*)(ws + 268959744ull);                     // 524,288
    float* Rr      = (float*)(ws + 269484032ull);                     // 524,288  (qg / F)
    float* Pr      = (float*)(ws + 270008320ull);                     // 524,288  (W3 / O)
    float* Qr      = (float*)(ws + 270532608ull);                     // 2,097,152 (gcomb|xn|hn / H1)
    float* upd_raw = (float*)(ws + 272629760ull);                     // 524,288
    float* rowsum  = (float*)(ws + 273154048ull);                     // 16,384
    unsigned short* W3 = (unsigned short*)Pr;
    float* O_  = Pr;
    float* gcomb = Qr;                    // 512x512
    float* xn = Qr + 262144;              // 512x256
    float* hn = Qr + 393216;              // 512x256
    float* H1 = Qr;                       // 512x256 (aliases gcomb, gB->gC dead by gD)
    float* qg = Rr;
    float* F_ = Rr;

    float* out_slots = (float*)d_out;            // [64,8,256]
    float* attn_out  = (float*)d_out + 131072;   // [64,8,8,4096]

    k_prep<<<512, 256, 0, stream>>>(wk, wv, W3);
    k_init<<<512, 256, 0, stream>>>(sm, slv, noise, slotsA);
    k_kv<<<4096, 256, 0, stream>>>(inputs, lniw, lnib, W3, bk, bv, Kb, Vb);
    for (int it = 0; it < 3; ++it) {
        int last = (it == 2);
        float* sl_in  = (it == 0) ? slotsA : ((it == 1) ? slotsB : slotsA);
        float* sl_out = (it == 0) ? slotsB : ((it == 1) ? slotsA : out_slots);
        k_q<<<512, 256, 0, stream>>>(sl_in, lnsw, lnsb, wq, bq, qg);
        k_attn<<<512, 512, 0, stream>>>(Kb, Vb, qg, upd_raw, rowsum, attn_out, last);
        k_gA<<<256, 256, 0, stream>>>(upd_raw, rowsum, wo, bo, O_);
        k_gB<<<384, 256, 0, stream>>>(O_, sl_in, wih, bih, whh, bhh, gcomb, xn, hn);
        k_gC<<<512, 256, 0, stream>>>(gcomb, xn, hn, sl_in, lnfw, lnfb, sl_out, F_);
        k_gD<<<256, 256, 0, stream>>>(F_, w1, b1, H1);
        k_gE<<<256, 256, 0, stream>>>(H1, w2, b2, sl_out);
    }
    k_scale<<<16384, 256, 0, stream>>>(attn_out, rowsum);
}